// Round 8
// baseline (23393.558 us; speedup 1.0000x reference)
//
#include <hip/hip_runtime.h>
#include <math.h>

#define Tt 512
#define Dd 768
#define Hh 512
#define Bb 32
#define G3 1536
#define HB (Hh*Bb)
#define NBLK 256
#define NTHR 512
#define NBAR (Tt*3)      // 3 grid barriers per step (S4 folded into S1 via p1 arrival counter)
#define PR 32   // state ring period (staleness window; 32 steps ~ 330MB through 4MB L2)

__device__ __forceinline__ float sigf(float x) { return 1.f / (1.f + expf(-x)); }

__device__ __forceinline__ float dot4f(const float4 w4, const float* v) {
  return w4.x*v[0] + w4.y*v[1] + w4.z*v[2] + w4.w*v[3];
}

// device-scope write-through store: lands at coherence point, no fence needed
__device__ __forceinline__ void dstore(float* p, float v) {
  __hip_atomic_store(p, v, __ATOMIC_RELAXED, __HIP_MEMORY_SCOPE_AGENT);
}
__device__ __forceinline__ unsigned dloadu(const unsigned* p) {
  return __hip_atomic_load(p, __ATOMIC_RELAXED, __HIP_MEMORY_SCOPE_AGENT);
}

// ---------------- grid barrier: relaxed monotone atomics, two-level tree ----
__device__ __forceinline__ void grid_barrier(unsigned* bc1, unsigned* bc2, unsigned* gfl, int idx)
{
  __syncthreads();
  if (threadIdx.x == 0) {
    const unsigned grp = (unsigned)(blockIdx.x >> 4);     // 16 groups x 16 blocks
    unsigned old = __hip_atomic_fetch_add(&bc1[((unsigned)idx * 16u + grp) * 16u], 1u,
                        __ATOMIC_RELAXED, __HIP_MEMORY_SCOPE_AGENT);
    if (old == 15u) {
      unsigned o2 = __hip_atomic_fetch_add(&bc2[(unsigned)idx * 16u], 1u,
                        __ATOMIC_RELAXED, __HIP_MEMORY_SCOPE_AGENT);
      if (o2 == 15u) {
#pragma unroll
        for (int g = 0; g < 16; ++g)
          __hip_atomic_store(&gfl[g * 16], (unsigned)(idx + 1),
                             __ATOMIC_RELAXED, __HIP_MEMORY_SCOPE_AGENT);
      }
    }
    while (__hip_atomic_load(&gfl[grp * 16], __ATOMIC_RELAXED, __HIP_MEMORY_SCOPE_AGENT)
           < (unsigned)(idx + 1))
      __builtin_amdgcn_s_sleep(1);
  }
  __syncthreads();
}

// ---------------- GI0 = x @ Wih0^T + bih0, layout [t][j][b] ----------------
__global__ __launch_bounds__(256) void gi0_gemm(const float* __restrict__ x,
                                                const float* __restrict__ Wih0,
                                                const float* __restrict__ bih0,
                                                float* __restrict__ GI0)
{
  const int t  = blockIdx.x;
  const int j0 = blockIdx.y * 128;
  const int tid = threadIdx.x;
  const int b = tid & 31, u = tid >> 5;

  __shared__ float xs[128][33];
  float acc[16];
#pragma unroll
  for (int jj = 0; jj < 16; jj++) acc[jj] = 0.f;

  for (int kbv = 0; kbv < Dd; kbv += 128) {
    __syncthreads();
    {
      int bb = tid >> 3, kg = (tid & 7) * 4;
      const float* xp = x + ((size_t)bb * Tt + t) * Dd + kbv;
#pragma unroll
      for (int q = 0; q < 4; q++) {
        float4 v = *(const float4*)(xp + kg + q * 32);
        int k = kg + q * 32;
        xs[k + 0][bb] = v.x; xs[k + 1][bb] = v.y;
        xs[k + 2][bb] = v.z; xs[k + 3][bb] = v.w;
      }
    }
    __syncthreads();
    for (int kk = 0; kk < 128; kk += 4) {
      float x0 = xs[kk][b], x1 = xs[kk + 1][b], x2 = xs[kk + 2][b], x3 = xs[kk + 3][b];
#pragma unroll
      for (int jj = 0; jj < 16; jj++) {
        const float* wp = Wih0 + (size_t)(j0 + u + 8 * jj) * Dd + kbv + kk;
        float4 w4 = *(const float4*)wp;
        acc[jj] += w4.x * x0 + w4.y * x1 + w4.z * x2 + w4.w * x3;
      }
    }
  }
#pragma unroll
  for (int jj = 0; jj < 16; jj++) {
    int j = j0 + u + 8 * jj;
    GI0[((size_t)t * G3 + j) * 32 + b] = acc[jj] + bih0[j];
  }
}

// ---------------- persistent HRNN kernel: 3 barriers/step ----------------
__global__ __launch_bounds__(NTHR, 1) void hrnn_persist(
    const float* __restrict__ Whh0, const float* __restrict__ bhh0,
    const float* __restrict__ Wih,  const float* __restrict__ Whh,
    const float* __restrict__ bih,  const float* __restrict__ bhh,
    const float* __restrict__ mW1,  const float* __restrict__ mb1,
    const float* __restrict__ mW2,  const float* __restrict__ mb2,
    const float* __restrict__ mW3,  const float* __restrict__ mb3,
    const float* __restrict__ GI0,
    float* __restrict__ c0R, float* __restrict__ c1R, float* __restrict__ c2R,
    float* __restrict__ m0aR, float* __restrict__ m1aR,
    float* __restrict__ pacc,
    unsigned* __restrict__ bc1, unsigned* __restrict__ bc2, unsigned* __restrict__ gfl,
    unsigned* __restrict__ cnt1, unsigned* __restrict__ cnt2,
    float* __restrict__ out)
{
  __shared__ float red[16][576];
  __shared__ float s_gh[12][32];
  __shared__ float s_pre[6][32];
  __shared__ float s_gi[6][32];
  __shared__ float s_mb[2][32];    // m0b or m1b columns of this block

  const int tid = threadIdx.x;
  const int b = tid & 31;
  const int u = tid >> 5;          // 0..15
  const int i0 = blockIdx.x * 2;
  const int kb = u * 32;
  const int grp = blockIdx.x >> 4;
  int baridx = 0;

  // hoisted scalars (uniform across steps)
  const float mb30 = mb3[0], mb31 = mb3[1];
  float w3p0 = 0.f, w3p1 = 0.f, w3q0 = 0.f, w3q1 = 0.f;
  if (tid >= 64 && tid < 96) {
    w3p0 = mW3[i0]; w3p1 = mW3[i0 + 1];
    w3q0 = mW3[512 + i0]; w3q1 = mW3[512 + i0 + 1];
  }

  for (int t = 0; t < Tt; t++) {
    const size_t wo = (size_t)(t & (PR - 1)) * HB;
    const size_t ro = (size_t)((t + PR - 1) & (PR - 1)) * HB;
    const float* c0o = c0R + ro;
    const float* c1o = c1R + ro;
    const float* c2o = c2R + ro;

    float a0, a1, a2, w10, w11;

    // ---- S1': publish p1(t-1) via arrival counter; weights; gh dots; cell0 ----
    {
      // tail prefetch: issue early so MALL latency overlaps everything below
      float pf0 = 0.f, pf1 = 0.f, pf2 = 0.f, gi_n = 0.f, gi_rz = 0.f;
      if (tid < 64) {
        int ii = tid >> 5, bb = tid & 31, idx = (i0 + ii) * 32 + bb;
        pf0 = c0o[idx]; pf1 = c1o[idx]; pf2 = c2o[idx];
        gi_n = GI0[((size_t)t * G3 + 1024 + i0 + ii) * 32 + bb];
      }
      if (tid < 128) {
        gi_rz = GI0[((size_t)t * G3 + (tid >> 6) * 512 + i0 + ((tid >> 5) & 1)) * 32 + (tid & 31)];
      }

      // early-issue first two state batches for (d): their MALL latency hides
      // under the m1b fold + counter + weight chain; (a)'s syncthreads drains
      // them for free. c0o/c1o/c2o are all old-slot (published >= 1 barrier ago).
      float va0[4], va1[4], va2[4], vb0[4], vb1[4], vb2[4];
#pragma unroll
      for (int q = 0; q < 4; q++) {
        va0[q] = c0o[(kb + q) * 32 + b];
        va1[q] = c1o[(kb + q) * 32 + b];
        va2[q] = c2o[(kb + q) * 32 + b];
      }
#pragma unroll
      for (int q = 0; q < 4; q++) {
        vb0[q] = c0o[(kb + 4 + q) * 32 + b];
        vb1[q] = c1o[(kb + 4 + q) * 32 + b];
        vb2[q] = c2o[(kb + 4 + q) * 32 + b];
      }

      if (t > 0) {
        // (a) m1b(t-1) over m1aR[slot t-1]; p1 partial -> pacc[t-1]; arrival counter
        const float* m1a = m1aR + ro;
        float acc2[2] = {0.f, 0.f};
        float vm[4];
#pragma unroll
        for (int q = 0; q < 4; q++) vm[q] = m1a[(kb + q) * 32 + b];
        for (int kk = 0; kk < 32; kk += 4) {
          float nm[4];
          {
            int kn = kb + ((kk + 4) & 31);
#pragma unroll
            for (int q = 0; q < 4; q++) nm[q] = m1a[(kn + q) * 32 + b];
          }
#pragma unroll
          for (int w = 0; w < 2; w++) {
            const float* wp = mW2 + (size_t)(512 + i0 + w) * 512;
            float4 w4 = *(const float4*)(wp + kb + kk);
            acc2[w] += dot4f(w4, vm);
          }
#pragma unroll
          for (int q = 0; q < 4; q++) vm[q] = nm[q];
        }
#pragma unroll
        for (int w = 0; w < 2; w++) red[u][w * 32 + b] = acc2[w];
        __syncthreads();
        if (tid < 64) {
          float s = 0.f;
#pragma unroll
          for (int uu = 0; uu < 16; uu++) s += red[uu][tid];
          int w = tid >> 5, b2 = tid & 31;
          s_mb[w][b2] = fmaxf(s + mb2[512 + i0 + w], 0.f);      // m1b cols
        }
        __syncthreads();
        if (tid >= 64 && tid < 96) {
          int b2 = tid - 64;
          float part = w3q0 * s_mb[0][b2] + w3q1 * s_mb[1][b2];
          __hip_atomic_fetch_add(&pacc[((size_t)(t - 1) * 2 + 1) * 512 + grp * 32 + b2], part,
                                 __ATOMIC_RELAXED, __HIP_MEMORY_SCOPE_AGENT);
        }
        __syncthreads();   // vmcnt(0) drain: p1 adds at coherence point before counter bump
        if (tid == 0) {
          unsigned o1 = __hip_atomic_fetch_add(&cnt1[((unsigned)(t - 1) * 16u + grp) * 16u], 1u,
                              __ATOMIC_RELAXED, __HIP_MEMORY_SCOPE_AGENT);
          if (o1 == 15u)
            __hip_atomic_fetch_add(&cnt2[(unsigned)(t - 1) * 16u], 1u,
                                   __ATOMIC_RELAXED, __HIP_MEMORY_SCOPE_AGENT);
          // (b) wait for all 16 groups' p1 contributions (normally already done)
          while (dloadu(&cnt2[(unsigned)(t - 1) * 16u]) < 16u)
            __builtin_amdgcn_s_sleep(1);
        }
        __syncthreads();
      }

      // (c) per-thread redundant softmax weights (no cross-thread sync)
      {
        const int pslot = (t + Tt - 1) & (Tt - 1);   // t=0 -> slot 511 (zeros)
        const float* pp0 = pacc + ((size_t)pslot * 2 + 0) * 512;
        const float* pp1 = pacc + ((size_t)pslot * 2 + 1) * 512;
        float s0 = mb30, s1 = mb31;
#pragma unroll
        for (int g = 0; g < 16; g++) { s0 += pp0[g * 32 + b]; s1 += pp1[g * 32 + b]; }
        float p0 = sigf(s0), p1 = sigf(s1);
        float e0 = expf(1.f - p0), e1 = expf(p0 * (1.f - p1)), e2 = expf(p0 * p1);
        float inv = 1.f / (e0 + e1 + e2);
        a0 = e0 * inv; a1 = e1 * inv; a2 = e2 * inv;
        float q0 = expf(1.f - p1), q1 = expf(p1);
        float qi = 1.f / (q0 + q1);
        w10 = q0 * qi; w11 = q1 * qi;
        if (t > 0 && blockIdx.x == 0 && tid < 32) {
          out[((size_t)tid * Tt + (t - 1)) * 2 + 0] = p0;
          out[((size_t)tid * Tt + (t - 1)) * 2 + 1] = p1;
        }
      }

      // (d) gh0/gh1/gh2 with inline h-mixing (distance-2 pipelined); cell0
      float acc[18];
#pragma unroll
      for (int w = 0; w < 18; w++) acc[w] = 0.f;
      for (int kk = 0; kk < 32; kk += 4) {
        float n0[4], n1[4], n2[4];
        {
          const int kn = kb + ((kk + 8) & 31);   // kk>=24: dummy cached re-read
#pragma unroll
          for (int q = 0; q < 4; q++) {
            n0[q] = c0o[(kn + q) * 32 + b];
            n1[q] = c1o[(kn + q) * 32 + b];
            n2[q] = c2o[(kn + q) * 32 + b];
          }
        }
        float mh0[4], mh1[4];
#pragma unroll
        for (int q = 0; q < 4; q++) {
          mh0[q] = a0 * va0[q] + a1 * va1[q] + a2 * va2[q];
          mh1[q] = w10 * va1[q] + w11 * va2[q];
        }
#pragma unroll
        for (int w = 0; w < 18; w++) {
          const int l = w / 6, rem = w % 6, g = rem >> 1, ii = rem & 1;
          const int row = g * 512 + i0 + ii;
          const float* wp = (l == 0) ? (Whh0 + (size_t)row * 512)
                                     : (Whh + ((size_t)(l - 1) * G3 + row) * 512);
          float4 w4 = *(const float4*)(wp + kb + kk);
          acc[w] += (l == 0) ? dot4f(w4, mh0) : (l == 1) ? dot4f(w4, mh1) : dot4f(w4, va2);
        }
#pragma unroll
        for (int q = 0; q < 4; q++) {
          va0[q] = vb0[q]; va1[q] = vb1[q]; va2[q] = vb2[q];
          vb0[q] = n0[q];  vb1[q] = n1[q];  vb2[q] = n2[q];
        }
      }
#pragma unroll
      for (int w = 0; w < 18; w++) red[u][w * 32 + b] = acc[w];
      __syncthreads();
      for (int o = tid; o < 18 * 32; o += NTHR) {
        float s = 0.f;
#pragma unroll
        for (int uu = 0; uu < 16; uu++) s += red[uu][o];
        int w = o >> 5, b2 = o & 31;
        int l = w / 6, rem = w % 6, g = rem >> 1, ii = rem & 1;
        int row = g * 512 + i0 + ii;
        if (l == 0) {
          s += bhh0[row];
          if (g < 2) s += gi_rz;          // prefetched GI0 r/z (first o-pass only)
          s_pre[rem][b2] = s;
        } else if (l == 1) {
          s_gh[rem][b2] = s + bhh[row];
        } else {
          s_gh[6 + rem][b2] = s + bhh[G3 + row];
        }
      }
      __syncthreads();
      if (tid < 64) {
        int ii = tid >> 5, bb = tid & 31;
        float r = sigf(s_pre[ii][bb]);
        float z = sigf(s_pre[2 + ii][bb]);
        float n = tanhf(gi_n + r * s_pre[4 + ii][bb]);
        int idx = (i0 + ii) * 32 + bb;
        float h0old = a0 * pf0 + a1 * pf1 + a2 * pf2;
        dstore(&c0R[wo + idx], (1.f - z) * n + z * h0old);
      }
    }
    grid_barrier(bc1, bc2, gfl, baridx++);

    // ---- S2: gi1 (over cell0) + m0a; cell1 ----
    {
      float pf1 = 0.f, pf2 = 0.f;
      if (tid < 64) {
        int ii = tid >> 5, bb = tid & 31, idx = (i0 + ii) * 32 + bb;
        pf1 = c1o[idx]; pf2 = c2o[idx];
      }
      const float* c0n = c0R + wo;
      float va[4], vb[4];
#pragma unroll
      for (int q = 0; q < 4; q++) va[q] = c0n[(kb + q) * 32 + b];
#pragma unroll
      for (int q = 0; q < 4; q++) vb[q] = c0n[(kb + 4 + q) * 32 + b];
      float acc[8];
#pragma unroll
      for (int w = 0; w < 8; w++) acc[w] = 0.f;
      for (int kk = 0; kk < 32; kk += 4) {
        float nv[4];
        {
          const int kn = kb + ((kk + 8) & 31);
#pragma unroll
          for (int q = 0; q < 4; q++) nv[q] = c0n[(kn + q) * 32 + b];
        }
#pragma unroll
        for (int w = 0; w < 8; w++) {
          const float* wp = (w < 6) ? (Wih + (size_t)((w >> 1) * 512 + i0 + (w & 1)) * 512)
                                    : (mW1 + (size_t)(i0 + (w - 6)) * 512);
          float4 w4 = *(const float4*)(wp + kb + kk);
          acc[w] += dot4f(w4, va);
        }
#pragma unroll
        for (int q = 0; q < 4; q++) { va[q] = vb[q]; vb[q] = nv[q]; }
      }
#pragma unroll
      for (int w = 0; w < 8; w++) red[u][w * 32 + b] = acc[w];
      __syncthreads();
      for (int o = tid; o < 8 * 32; o += NTHR) {
        float s = 0.f;
#pragma unroll
        for (int uu = 0; uu < 16; uu++) s += red[uu][o];
        int w = o >> 5, b2 = o & 31;
        if (w < 6) {
          int row = (w >> 1) * 512 + i0 + (w & 1);
          s_gi[w][b2] = s + bih[row];
        } else {
          int col = i0 + (w - 6);
          dstore(&m0aR[wo + col * 32 + b2], fmaxf(s + mb1[col], 0.f));
        }
      }
      __syncthreads();
      if (tid < 64) {
        int ii = tid >> 5, bb = tid & 31;
        float r = sigf(s_gi[ii][bb] + s_gh[ii][bb]);
        float z = sigf(s_gi[2 + ii][bb] + s_gh[2 + ii][bb]);
        float n = tanhf(s_gi[4 + ii][bb] + r * s_gh[4 + ii][bb]);
        int idx = (i0 + ii) * 32 + bb;
        float h1old = w10 * pf1 + w11 * pf2;
        dstore(&c1R[wo + idx], (1.f - z) * n + z * h1old);
      }
    }
    grid_barrier(bc1, bc2, gfl, baridx++);

    // ---- S3: gi2 (over cell1) + m0b (over m0a) + m1a (over cell1); cell2; p0 partials ----
    {
      float pf2 = 0.f;
      if (tid < 64) {
        int ii = tid >> 5, bb = tid & 31;
        pf2 = c2o[(i0 + ii) * 32 + bb];
      }
      const float* c1n = c1R + wo;
      const float* m0a = m0aR + wo;
      float va[4], vma[4], vb[4], vmb[4];
#pragma unroll
      for (int q = 0; q < 4; q++) {
        va[q]  = c1n[(kb + q) * 32 + b];
        vma[q] = m0a[(kb + q) * 32 + b];
      }
#pragma unroll
      for (int q = 0; q < 4; q++) {
        vb[q]  = c1n[(kb + 4 + q) * 32 + b];
        vmb[q] = m0a[(kb + 4 + q) * 32 + b];
      }
      float acc[10];
#pragma unroll
      for (int w = 0; w < 10; w++) acc[w] = 0.f;
      for (int kk = 0; kk < 32; kk += 4) {
        float nv[4], nm[4];
        {
          const int kn = kb + ((kk + 8) & 31);
#pragma unroll
          for (int q = 0; q < 4; q++) {
            nv[q] = c1n[(kn + q) * 32 + b];
            nm[q] = m0a[(kn + q) * 32 + b];
          }
        }
#pragma unroll
        for (int w = 0; w < 10; w++) {
          const float* wp = (w < 6) ? (Wih + (size_t)(G3 + (w >> 1) * 512 + i0 + (w & 1)) * 512)
                          : (w < 8) ? (mW2 + (size_t)(i0 + (w - 6)) * 512)
                                    : (mW1 + (size_t)(512 + i0 + (w - 8)) * 512);
          float4 w4 = *(const float4*)(wp + kb + kk);
          acc[w] += dot4f(w4, (w < 6 || w >= 8) ? va : vma);
        }
#pragma unroll
        for (int q = 0; q < 4; q++) {
          va[q] = vb[q];  vma[q] = vmb[q];
          vb[q] = nv[q];  vmb[q] = nm[q];
        }
      }
#pragma unroll
      for (int w = 0; w < 10; w++) red[u][w * 32 + b] = acc[w];
      __syncthreads();
      for (int o = tid; o < 10 * 32; o += NTHR) {
        float s = 0.f;
#pragma unroll
        for (int uu = 0; uu < 16; uu++) s += red[uu][o];
        int w = o >> 5, b2 = o & 31;
        if (w < 6) {
          int row = (w >> 1) * 512 + i0 + (w & 1);
          s_gi[w][b2] = s + bih[G3 + row];
        } else if (w < 8) {
          s_mb[w - 6][b2] = fmaxf(s + mb2[i0 + (w - 6)], 0.f);   // m0b cols
        } else {
          int col = i0 + (w - 8);
          dstore(&m1aR[wo + col * 32 + b2], fmaxf(s + mb1[512 + col], 0.f));
        }
      }
      __syncthreads();
      if (tid < 64) {
        int ii = tid >> 5, bb = tid & 31;
        float r = sigf(s_gi[ii][bb] + s_gh[6 + ii][bb]);
        float z = sigf(s_gi[2 + ii][bb] + s_gh[8 + ii][bb]);
        float n = tanhf(s_gi[4 + ii][bb] + r * s_gh[10 + ii][bb]);
        int idx = (i0 + ii) * 32 + bb;
        dstore(&c2R[wo + idx], (1.f - z) * n + z * pf2);
      } else if (tid < 96) {
        int b2 = tid - 64;
        float part = w3p0 * s_mb[0][b2] + w3p1 * s_mb[1][b2];
        __hip_atomic_fetch_add(&pacc[((size_t)t * 2 + 0) * 512 + grp * 32 + b2], part,
                               __ATOMIC_RELAXED, __HIP_MEMORY_SCOPE_AGENT);
      }
    }
    grid_barrier(bc1, bc2, gfl, baridx++);
  }

  // ---- epilogue: publish p1(T-1) and write final out column ----
  {
    const size_t rofin = (size_t)((Tt - 1) & (PR - 1)) * HB;
    const float* m1a = m1aR + rofin;
    float acc2[2] = {0.f, 0.f};
    for (int kk = 0; kk < 32; kk += 4) {
      float vm[4];
#pragma unroll
      for (int q = 0; q < 4; q++) vm[q] = m1a[(kb + kk + q) * 32 + b];
#pragma unroll
      for (int w = 0; w < 2; w++) {
        const float* wp = mW2 + (size_t)(512 + i0 + w) * 512;
        float4 w4 = *(const float4*)(wp + kb + kk);
        acc2[w] += dot4f(w4, vm);
      }
    }
#pragma unroll
    for (int w = 0; w < 2; w++) red[u][w * 32 + b] = acc2[w];
    __syncthreads();
    if (tid < 64) {
      float s = 0.f;
#pragma unroll
      for (int uu = 0; uu < 16; uu++) s += red[uu][tid];
      int w = tid >> 5, b2 = tid & 31;
      s_mb[w][b2] = fmaxf(s + mb2[512 + i0 + w], 0.f);
    }
    __syncthreads();
    if (tid >= 64 && tid < 96) {
      int b2 = tid - 64;
      float part = w3q0 * s_mb[0][b2] + w3q1 * s_mb[1][b2];
      __hip_atomic_fetch_add(&pacc[((size_t)(Tt - 1) * 2 + 1) * 512 + grp * 32 + b2], part,
                             __ATOMIC_RELAXED, __HIP_MEMORY_SCOPE_AGENT);
    }
    __syncthreads();   // drain p1 adds before counter bump
    if (tid == 0) {
      unsigned o1 = __hip_atomic_fetch_add(&cnt1[((unsigned)(Tt - 1) * 16u + grp) * 16u], 1u,
                          __ATOMIC_RELAXED, __HIP_MEMORY_SCOPE_AGENT);
      if (o1 == 15u)
        __hip_atomic_fetch_add(&cnt2[(unsigned)(Tt - 1) * 16u], 1u,
                               __ATOMIC_RELAXED, __HIP_MEMORY_SCOPE_AGENT);
    }
    if (blockIdx.x == 0) {
      if (tid == 0) {
        while (dloadu(&cnt2[(unsigned)(Tt - 1) * 16u]) < 16u)
          __builtin_amdgcn_s_sleep(1);
      }
      __syncthreads();
      if (tid < 32) {
        const float* pp0 = pacc + ((size_t)(Tt - 1) * 2 + 0) * 512;
        const float* pp1 = pacc + ((size_t)(Tt - 1) * 2 + 1) * 512;
        float s0 = mb30, s1 = mb31;
#pragma unroll
        for (int g = 0; g < 16; g++) { s0 += pp0[g * 32 + tid]; s1 += pp1[g * 32 + tid]; }
        out[((size_t)tid * Tt + (Tt - 1)) * 2 + 0] = sigf(s0);
        out[((size_t)tid * Tt + (Tt - 1)) * 2 + 1] = sigf(s1);
      }
    }
  }
}

extern "C" void kernel_launch(void* const* d_in, const int* in_sizes, int n_in,
                              void* d_out, int out_size, void* d_ws, size_t ws_size,
                              hipStream_t stream)
{
  (void)in_sizes; (void)n_in; (void)out_size;
  const float* x    = (const float*)d_in[0];
  const float* Wih0 = (const float*)d_in[1];
  const float* Whh0 = (const float*)d_in[2];
  const float* bih0 = (const float*)d_in[3];
  const float* bhh0 = (const float*)d_in[4];
  const float* Wih  = (const float*)d_in[5];
  const float* Whh  = (const float*)d_in[6];
  const float* bih  = (const float*)d_in[7];
  const float* bhh  = (const float*)d_in[8];
  const float* mW1  = (const float*)d_in[9];
  const float* mb1  = (const float*)d_in[10];
  const float* mW2  = (const float*)d_in[11];
  const float* mb2  = (const float*)d_in[12];
  const float* mW3  = (const float*)d_in[13];
  const float* mb3  = (const float*)d_in[14];
  float* out = (float*)d_out;

  char* ws = (char*)d_ws;
  size_t off = 0;
  auto take = [&](size_t bytes) { size_t o = off; off = (off + bytes + 255) & ~(size_t)255; return o; };
  unsigned* bc1  = (unsigned*)(ws + take((size_t)NBAR * 16 * 16 * 4));
  unsigned* bc2  = (unsigned*)(ws + take((size_t)NBAR * 16 * 4));
  unsigned* gfl  = (unsigned*)(ws + take((size_t)16 * 16 * 4));
  unsigned* cnt1 = (unsigned*)(ws + take((size_t)Tt * 16 * 16 * 4));
  unsigned* cnt2 = (unsigned*)(ws + take((size_t)Tt * 16 * 4));
  float* c0R  = (float*)(ws + take((size_t)PR * HB * 4));
  float* c1R  = (float*)(ws + take((size_t)PR * HB * 4));
  float* c2R  = (float*)(ws + take((size_t)PR * HB * 4));
  float* m0aR = (float*)(ws + take((size_t)PR * HB * 4));
  float* m1aR = (float*)(ws + take((size_t)PR * HB * 4));
  float* pacc = (float*)(ws + take((size_t)Tt * 2 * 512 * 4));
  size_t zero_bytes = off;
  float* GI0 = (float*)(ws + take((size_t)Tt * G3 * Bb * 4));
  if (ws_size < off) return;  // fail visibly rather than corrupt

  hipMemsetAsync(d_ws, 0, zero_bytes, stream);
  gi0_gemm<<<dim3(Tt, G3 / 128), 256, 0, stream>>>(x, Wih0, bih0, GI0);
  hrnn_persist<<<NBLK, NTHR, 0, stream>>>(Whh0, bhh0, Wih, Whh, bih, bhh,
      mW1, mb1, mW2, mb2, mW3, mb3, GI0,
      c0R, c1R, c2R, m0aR, m1aR, pacc, bc1, bc2, gfl, cnt1, cnt2, out);
}

// Round 9
// 21178.668 us; speedup vs baseline: 1.1046x; 1.1046x over previous
//
#include <hip/hip_runtime.h>
#include <math.h>

#define Tt 512
#define Dd 768
#define Hh 512
#define Bb 32
#define G3 1536
#define HB (Hh*Bb)
#define NBLK 256
#define NTHR 512
#define NBAR (Tt*3)      // 3 grid barriers per step (S4 folded into S1 via p1 arrival counter)
#define PR 32   // state ring period (staleness window; 32 steps ~ 330MB through 4MB L2)

__device__ __forceinline__ float sigf(float x) { return 1.f / (1.f + expf(-x)); }

__device__ __forceinline__ float dot4f(const float4 w4, const float* v) {
  return w4.x*v[0] + w4.y*v[1] + w4.z*v[2] + w4.w*v[3];
}

// device-scope write-through store: lands at coherence point, no fence needed
__device__ __forceinline__ void dstore(float* p, float v) {
  __hip_atomic_store(p, v, __ATOMIC_RELAXED, __HIP_MEMORY_SCOPE_AGENT);
}
__device__ __forceinline__ unsigned dloadu(const unsigned* p) {
  return __hip_atomic_load(p, __ATOMIC_RELAXED, __HIP_MEMORY_SCOPE_AGENT);
}

// ---------------- grid barrier: relaxed monotone atomics, two-level tree ----
__device__ __forceinline__ void grid_barrier(unsigned* bc1, unsigned* bc2, unsigned* gfl, int idx)
{
  __syncthreads();
  if (threadIdx.x == 0) {
    const unsigned grp = (unsigned)(blockIdx.x >> 4);     // 16 groups x 16 blocks
    unsigned old = __hip_atomic_fetch_add(&bc1[((unsigned)idx * 16u + grp) * 16u], 1u,
                        __ATOMIC_RELAXED, __HIP_MEMORY_SCOPE_AGENT);
    if (old == 15u) {
      unsigned o2 = __hip_atomic_fetch_add(&bc2[(unsigned)idx * 16u], 1u,
                        __ATOMIC_RELAXED, __HIP_MEMORY_SCOPE_AGENT);
      if (o2 == 15u) {
#pragma unroll
        for (int g = 0; g < 16; ++g)
          __hip_atomic_store(&gfl[g * 16], (unsigned)(idx + 1),
                             __ATOMIC_RELAXED, __HIP_MEMORY_SCOPE_AGENT);
      }
    }
    while (__hip_atomic_load(&gfl[grp * 16], __ATOMIC_RELAXED, __HIP_MEMORY_SCOPE_AGENT)
           < (unsigned)(idx + 1))
      __builtin_amdgcn_s_sleep(1);
  }
  __syncthreads();
}

// ---------------- GI0 = x @ Wih0^T + bih0, layout [t][j][b] ----------------
__global__ __launch_bounds__(256) void gi0_gemm(const float* __restrict__ x,
                                                const float* __restrict__ Wih0,
                                                const float* __restrict__ bih0,
                                                float* __restrict__ GI0)
{
  const int t  = blockIdx.x;
  const int j0 = blockIdx.y * 128;
  const int tid = threadIdx.x;
  const int b = tid & 31, u = tid >> 5;

  __shared__ float xs[128][33];
  float acc[16];
#pragma unroll
  for (int jj = 0; jj < 16; jj++) acc[jj] = 0.f;

  for (int kbv = 0; kbv < Dd; kbv += 128) {
    __syncthreads();
    {
      int bb = tid >> 3, kg = (tid & 7) * 4;
      const float* xp = x + ((size_t)bb * Tt + t) * Dd + kbv;
#pragma unroll
      for (int q = 0; q < 4; q++) {
        float4 v = *(const float4*)(xp + kg + q * 32);
        int k = kg + q * 32;
        xs[k + 0][bb] = v.x; xs[k + 1][bb] = v.y;
        xs[k + 2][bb] = v.z; xs[k + 3][bb] = v.w;
      }
    }
    __syncthreads();
    for (int kk = 0; kk < 128; kk += 4) {
      float x0 = xs[kk][b], x1 = xs[kk + 1][b], x2 = xs[kk + 2][b], x3 = xs[kk + 3][b];
#pragma unroll
      for (int jj = 0; jj < 16; jj++) {
        const float* wp = Wih0 + (size_t)(j0 + u + 8 * jj) * Dd + kbv + kk;
        float4 w4 = *(const float4*)wp;
        acc[jj] += w4.x * x0 + w4.y * x1 + w4.z * x2 + w4.w * x3;
      }
    }
  }
#pragma unroll
  for (int jj = 0; jj < 16; jj++) {
    int j = j0 + u + 8 * jj;
    GI0[((size_t)t * G3 + j) * 32 + b] = acc[jj] + bih0[j];
  }
}

// ---------------- persistent HRNN kernel: 3 barriers/step ----------------
__global__ __launch_bounds__(NTHR, 1) void hrnn_persist(
    const float* __restrict__ Whh0, const float* __restrict__ bhh0,
    const float* __restrict__ Wih,  const float* __restrict__ Whh,
    const float* __restrict__ bih,  const float* __restrict__ bhh,
    const float* __restrict__ mW1,  const float* __restrict__ mb1,
    const float* __restrict__ mW2,  const float* __restrict__ mb2,
    const float* __restrict__ mW3,  const float* __restrict__ mb3,
    const float* __restrict__ GI0,
    float* __restrict__ c0R, float* __restrict__ c1R, float* __restrict__ c2R,
    float* __restrict__ m0aR, float* __restrict__ m1aR,
    float* __restrict__ pacc,
    unsigned* __restrict__ bc1, unsigned* __restrict__ bc2, unsigned* __restrict__ gfl,
    unsigned* __restrict__ cnt1, unsigned* __restrict__ cnt2,
    float* __restrict__ out)
{
  __shared__ float red[16][576];
  __shared__ float s_gh[12][32];
  __shared__ float s_pre[6][32];
  __shared__ float s_gi[6][32];
  __shared__ float s_mb[2][32];    // m0b or m1b columns of this block

  const int tid = threadIdx.x;
  const int b = tid & 31;
  const int u = tid >> 5;          // 0..15
  const int i0 = blockIdx.x * 2;
  const int kb = u * 32;
  const int grp = blockIdx.x >> 4;
  int baridx = 0;

  // hoisted scalars (uniform across steps)
  const float mb30 = mb3[0], mb31 = mb3[1];
  float w3p0 = 0.f, w3p1 = 0.f, w3q0 = 0.f, w3q1 = 0.f;
  if (tid >= 64 && tid < 96) {
    w3p0 = mW3[i0]; w3p1 = mW3[i0 + 1];
    w3q0 = mW3[512 + i0]; w3q1 = mW3[512 + i0 + 1];
  }

  for (int t = 0; t < Tt; t++) {
    const size_t wo = (size_t)(t & (PR - 1)) * HB;
    const size_t ro = (size_t)((t + PR - 1) & (PR - 1)) * HB;
    const float* c0o = c0R + ro;
    const float* c1o = c1R + ro;
    const float* c2o = c2R + ro;

    float a0, a1, a2, w10, w11;

    // ---- S1': publish p1(t-1); gh2 dots hide counter propagation; weights; gh0/gh1; cell0 ----
    {
      // tail prefetch: issue early so MALL latency overlaps everything below
      float pf0 = 0.f, pf1 = 0.f, pf2 = 0.f, gi_n = 0.f, gi_rz = 0.f;
      if (tid < 64) {
        int ii = tid >> 5, bb = tid & 31, idx = (i0 + ii) * 32 + bb;
        pf0 = c0o[idx]; pf1 = c1o[idx]; pf2 = c2o[idx];
        gi_n = GI0[((size_t)t * G3 + 1024 + i0 + ii) * 32 + bb];
      }
      if (tid < 128) {
        gi_rz = GI0[((size_t)t * G3 + (tid >> 6) * 512 + i0 + ((tid >> 5) & 1)) * 32 + (tid & 31)];
      }

      if (t > 0) {
        // (a) m1b(t-1) over m1aR[slot t-1]; p1 partial -> pacc[t-1]; counter bump
        const float* m1a = m1aR + ro;
        float acc2[2] = {0.f, 0.f};
        float vm[4];
#pragma unroll
        for (int q = 0; q < 4; q++) vm[q] = m1a[(kb + q) * 32 + b];
        for (int kk = 0; kk < 32; kk += 4) {
          float nm[4];
          {
            int kn = kb + (kk < 28 ? kk + 4 : 4);
#pragma unroll
            for (int q = 0; q < 4; q++) nm[q] = m1a[(kn + q) * 32 + b];
          }
#pragma unroll
          for (int w = 0; w < 2; w++) {
            const float* wp = mW2 + (size_t)(512 + i0 + w) * 512;
            float4 w4 = *(const float4*)(wp + kb + kk);
            acc2[w] += dot4f(w4, vm);
          }
#pragma unroll
          for (int q = 0; q < 4; q++) vm[q] = nm[q];
        }
#pragma unroll
        for (int w = 0; w < 2; w++) red[u][w * 32 + b] = acc2[w];
        __syncthreads();
        if (tid < 64) {
          float s = 0.f;
#pragma unroll
          for (int uu = 0; uu < 16; uu++) s += red[uu][tid];
          int w = tid >> 5, b2 = tid & 31;
          s_mb[w][b2] = fmaxf(s + mb2[512 + i0 + w], 0.f);      // m1b cols
        }
        __syncthreads();
        if (tid >= 64 && tid < 96) {
          int b2 = tid - 64;
          float part = w3q0 * s_mb[0][b2] + w3q1 * s_mb[1][b2];
          __hip_atomic_fetch_add(&pacc[((size_t)(t - 1) * 2 + 1) * 512 + grp * 32 + b2], part,
                                 __ATOMIC_RELAXED, __HIP_MEMORY_SCOPE_AGENT);
        }
        __syncthreads();   // vmcnt(0) drain: p1 adds at coherence point before counter bump
        if (tid == 0) {
          unsigned o1 = __hip_atomic_fetch_add(&cnt1[((unsigned)(t - 1) * 16u + grp) * 16u], 1u,
                              __ATOMIC_RELAXED, __HIP_MEMORY_SCOPE_AGENT);
          if (o1 == 15u)
            __hip_atomic_fetch_add(&cnt2[(unsigned)(t - 1) * 16u], 1u,
                                   __ATOMIC_RELAXED, __HIP_MEMORY_SCOPE_AGENT);
          // poll deferred: gh2 dots below hide the counter propagation
        }
      }

      // (b') gh2 = Whh2 @ c2o — weight-independent, runs between bump and poll.
      // c2 is re-read in (d) for the h-mix; the gap spans only the weight chain
      // (~2MB/XCD intervening) so the re-read stays L2-hot.
      float acc2v[6];
#pragma unroll
      for (int w = 0; w < 6; w++) acc2v[w] = 0.f;
      {
        float v2[4];
#pragma unroll
        for (int q = 0; q < 4; q++) v2[q] = c2o[(kb + q) * 32 + b];
        for (int kk = 0; kk < 32; kk += 4) {
          float n2[4];
          {
            int kn = kb + (kk < 28 ? kk + 4 : 4);   // last iter: dummy cached re-read
#pragma unroll
            for (int q = 0; q < 4; q++) n2[q] = c2o[(kn + q) * 32 + b];
          }
#pragma unroll
          for (int w = 0; w < 6; w++) {
            const int row = (w >> 1) * 512 + i0 + (w & 1);
            const float* wp = Whh + (size_t)(G3 + row) * 512;
            float4 w4 = *(const float4*)(wp + kb + kk);
            acc2v[w] += dot4f(w4, v2);
          }
#pragma unroll
          for (int q = 0; q < 4; q++) v2[q] = n2[q];
        }
      }

      if (t > 0) {
        if (tid == 0) {
          // wait for all 16 groups' p1 contributions (normally already landed)
          while (dloadu(&cnt2[(unsigned)(t - 1) * 16u]) < 16u)
            __builtin_amdgcn_s_sleep(1);
        }
        __syncthreads();
      }

      // (c) per-thread redundant softmax weights (no cross-thread sync)
      {
        const int pslot = (t + Tt - 1) & (Tt - 1);   // t=0 -> slot 511 (zeros)
        const float* pp0 = pacc + ((size_t)pslot * 2 + 0) * 512;
        const float* pp1 = pacc + ((size_t)pslot * 2 + 1) * 512;
        float s0 = mb30, s1 = mb31;
#pragma unroll
        for (int g = 0; g < 16; g++) { s0 += pp0[g * 32 + b]; s1 += pp1[g * 32 + b]; }
        float p0 = sigf(s0), p1 = sigf(s1);
        float e0 = expf(1.f - p0), e1 = expf(p0 * (1.f - p1)), e2 = expf(p0 * p1);
        float inv = 1.f / (e0 + e1 + e2);
        a0 = e0 * inv; a1 = e1 * inv; a2 = e2 * inv;
        float q0 = expf(1.f - p1), q1 = expf(p1);
        float qi = 1.f / (q0 + q1);
        w10 = q0 * qi; w11 = q1 * qi;
        if (t > 0 && blockIdx.x == 0 && tid < 32) {
          out[((size_t)tid * Tt + (t - 1)) * 2 + 0] = p0;
          out[((size_t)tid * Tt + (t - 1)) * 2 + 1] = p1;
        }
      }

      // (d) gh0/gh1 with inline h-mixing (distance-1 pipelined); cell0
      float acc[12];
#pragma unroll
      for (int w = 0; w < 12; w++) acc[w] = 0.f;
      float v0[4], v1[4], v2[4];
#pragma unroll
      for (int q = 0; q < 4; q++) {
        int k = kb + q;
        v0[q] = c0o[k * 32 + b]; v1[q] = c1o[k * 32 + b]; v2[q] = c2o[k * 32 + b];
      }
      for (int kk = 0; kk < 32; kk += 4) {
        float n0[4], n1[4], n2[4];
        {
          int kn = kb + (kk < 28 ? kk + 4 : 4);   // last iter: dummy cached re-read
#pragma unroll
          for (int q = 0; q < 4; q++) {
            n0[q] = c0o[(kn + q) * 32 + b];
            n1[q] = c1o[(kn + q) * 32 + b];
            n2[q] = c2o[(kn + q) * 32 + b];
          }
        }
        float mh0[4], mh1[4];
#pragma unroll
        for (int q = 0; q < 4; q++) {
          mh0[q] = a0 * v0[q] + a1 * v1[q] + a2 * v2[q];
          mh1[q] = w10 * v1[q] + w11 * v2[q];
        }
#pragma unroll
        for (int w = 0; w < 12; w++) {
          const int l = w / 6, rem = w % 6, g = rem >> 1, ii = rem & 1;
          const int row = g * 512 + i0 + ii;
          const float* wp = (l == 0) ? (Whh0 + (size_t)row * 512)
                                     : (Whh + (size_t)row * 512);
          float4 w4 = *(const float4*)(wp + kb + kk);
          acc[w] += (l == 0) ? dot4f(w4, mh0) : dot4f(w4, mh1);
        }
#pragma unroll
        for (int q = 0; q < 4; q++) { v0[q] = n0[q]; v1[q] = n1[q]; v2[q] = n2[q]; }
      }
#pragma unroll
      for (int w = 0; w < 12; w++) red[u][w * 32 + b] = acc[w];
#pragma unroll
      for (int w = 0; w < 6; w++) red[u][(12 + w) * 32 + b] = acc2v[w];
      __syncthreads();
      for (int o = tid; o < 18 * 32; o += NTHR) {
        float s = 0.f;
#pragma unroll
        for (int uu = 0; uu < 16; uu++) s += red[uu][o];
        int w = o >> 5, b2 = o & 31;
        int l = w / 6, rem = w % 6, g = rem >> 1, ii = rem & 1;
        int row = g * 512 + i0 + ii;
        if (l == 0) {
          s += bhh0[row];
          if (g < 2) s += gi_rz;          // prefetched GI0 r/z (first o-pass only)
          s_pre[rem][b2] = s;
        } else if (l == 1) {
          s_gh[rem][b2] = s + bhh[row];
        } else {
          s_gh[6 + rem][b2] = s + bhh[G3 + row];
        }
      }
      __syncthreads();
      if (tid < 64) {
        int ii = tid >> 5, bb = tid & 31;
        float r = sigf(s_pre[ii][bb]);
        float z = sigf(s_pre[2 + ii][bb]);
        float n = tanhf(gi_n + r * s_pre[4 + ii][bb]);
        int idx = (i0 + ii) * 32 + bb;
        float h0old = a0 * pf0 + a1 * pf1 + a2 * pf2;
        dstore(&c0R[wo + idx], (1.f - z) * n + z * h0old);
      }
    }
    grid_barrier(bc1, bc2, gfl, baridx++);

    // ---- S2: gi1 (over cell0) + m0a; cell1 ----
    {
      float pf1 = 0.f, pf2 = 0.f;
      if (tid < 64) {
        int ii = tid >> 5, bb = tid & 31, idx = (i0 + ii) * 32 + bb;
        pf1 = c1o[idx]; pf2 = c2o[idx];
      }
      const float* c0n = c0R + wo;
      float acc[8];
#pragma unroll
      for (int w = 0; w < 8; w++) acc[w] = 0.f;
      float v[4];
#pragma unroll
      for (int q = 0; q < 4; q++) v[q] = c0n[(kb + q) * 32 + b];
      for (int kk = 0; kk < 32; kk += 4) {
        float nv[4];
        {
          int kn = kb + (kk < 28 ? kk + 4 : 4);
#pragma unroll
          for (int q = 0; q < 4; q++) nv[q] = c0n[(kn + q) * 32 + b];
        }
#pragma unroll
        for (int w = 0; w < 8; w++) {
          const float* wp = (w < 6) ? (Wih + (size_t)((w >> 1) * 512 + i0 + (w & 1)) * 512)
                                    : (mW1 + (size_t)(i0 + (w - 6)) * 512);
          float4 w4 = *(const float4*)(wp + kb + kk);
          acc[w] += dot4f(w4, v);
        }
#pragma unroll
        for (int q = 0; q < 4; q++) v[q] = nv[q];
      }
#pragma unroll
      for (int w = 0; w < 8; w++) red[u][w * 32 + b] = acc[w];
      __syncthreads();
      for (int o = tid; o < 8 * 32; o += NTHR) {
        float s = 0.f;
#pragma unroll
        for (int uu = 0; uu < 16; uu++) s += red[uu][o];
        int w = o >> 5, b2 = o & 31;
        if (w < 6) {
          int row = (w >> 1) * 512 + i0 + (w & 1);
          s_gi[w][b2] = s + bih[row];
        } else {
          int col = i0 + (w - 6);
          dstore(&m0aR[wo + col * 32 + b2], fmaxf(s + mb1[col], 0.f));
        }
      }
      __syncthreads();
      if (tid < 64) {
        int ii = tid >> 5, bb = tid & 31;
        float r = sigf(s_gi[ii][bb] + s_gh[ii][bb]);
        float z = sigf(s_gi[2 + ii][bb] + s_gh[2 + ii][bb]);
        float n = tanhf(s_gi[4 + ii][bb] + r * s_gh[4 + ii][bb]);
        int idx = (i0 + ii) * 32 + bb;
        float h1old = w10 * pf1 + w11 * pf2;
        dstore(&c1R[wo + idx], (1.f - z) * n + z * h1old);
      }
    }
    grid_barrier(bc1, bc2, gfl, baridx++);

    // ---- S3: gi2 (over cell1) + m0b (over m0a) + m1a (over cell1); cell2; p0 partials ----
    {
      float pf2 = 0.f;
      if (tid < 64) {
        int ii = tid >> 5, bb = tid & 31;
        pf2 = c2o[(i0 + ii) * 32 + bb];
      }
      const float* c1n = c1R + wo;
      const float* m0a = m0aR + wo;
      float acc[10];
#pragma unroll
      for (int w = 0; w < 10; w++) acc[w] = 0.f;
      float v[4], vm[4];
#pragma unroll
      for (int q = 0; q < 4; q++) {
        v[q]  = c1n[(kb + q) * 32 + b];
        vm[q] = m0a[(kb + q) * 32 + b];
      }
      for (int kk = 0; kk < 32; kk += 4) {
        float nv[4], nm[4];
        {
          int kn = kb + (kk < 28 ? kk + 4 : 4);
#pragma unroll
          for (int q = 0; q < 4; q++) {
            nv[q] = c1n[(kn + q) * 32 + b];
            nm[q] = m0a[(kn + q) * 32 + b];
          }
        }
#pragma unroll
        for (int w = 0; w < 10; w++) {
          const float* wp = (w < 6) ? (Wih + (size_t)(G3 + (w >> 1) * 512 + i0 + (w & 1)) * 512)
                          : (w < 8) ? (mW2 + (size_t)(i0 + (w - 6)) * 512)
                                    : (mW1 + (size_t)(512 + i0 + (w - 8)) * 512);
          float4 w4 = *(const float4*)(wp + kb + kk);
          acc[w] += dot4f(w4, (w < 6 || w >= 8) ? v : vm);
        }
#pragma unroll
        for (int q = 0; q < 4; q++) { v[q] = nv[q]; vm[q] = nm[q]; }
      }
#pragma unroll
      for (int w = 0; w < 10; w++) red[u][w * 32 + b] = acc[w];
      __syncthreads();
      for (int o = tid; o < 10 * 32; o += NTHR) {
        float s = 0.f;
#pragma unroll
        for (int uu = 0; uu < 16; uu++) s += red[uu][o];
        int w = o >> 5, b2 = o & 31;
        if (w < 6) {
          int row = (w >> 1) * 512 + i0 + (w & 1);
          s_gi[w][b2] = s + bih[G3 + row];
        } else if (w < 8) {
          s_mb[w - 6][b2] = fmaxf(s + mb2[i0 + (w - 6)], 0.f);   // m0b cols
        } else {
          int col = i0 + (w - 8);
          dstore(&m1aR[wo + col * 32 + b2], fmaxf(s + mb1[512 + col], 0.f));
        }
      }
      __syncthreads();
      if (tid < 64) {
        int ii = tid >> 5, bb = tid & 31;
        float r = sigf(s_gi[ii][bb] + s_gh[6 + ii][bb]);
        float z = sigf(s_gi[2 + ii][bb] + s_gh[8 + ii][bb]);
        float n = tanhf(s_gi[4 + ii][bb] + r * s_gh[10 + ii][bb]);
        int idx = (i0 + ii) * 32 + bb;
        dstore(&c2R[wo + idx], (1.f - z) * n + z * pf2);
      } else if (tid < 96) {
        int b2 = tid - 64;
        float part = w3p0 * s_mb[0][b2] + w3p1 * s_mb[1][b2];
        __hip_atomic_fetch_add(&pacc[((size_t)t * 2 + 0) * 512 + grp * 32 + b2], part,
                               __ATOMIC_RELAXED, __HIP_MEMORY_SCOPE_AGENT);
      }
    }
    grid_barrier(bc1, bc2, gfl, baridx++);
  }

  // ---- epilogue: publish p1(T-1) and write final out column ----
  {
    const size_t rofin = (size_t)((Tt - 1) & (PR - 1)) * HB;
    const float* m1a = m1aR + rofin;
    float acc2[2] = {0.f, 0.f};
    for (int kk = 0; kk < 32; kk += 4) {
      float vm[4];
#pragma unroll
      for (int q = 0; q < 4; q++) vm[q] = m1a[(kb + kk + q) * 32 + b];
#pragma unroll
      for (int w = 0; w < 2; w++) {
        const float* wp = mW2 + (size_t)(512 + i0 + w) * 512;
        float4 w4 = *(const float4*)(wp + kb + kk);
        acc2[w] += dot4f(w4, vm);
      }
    }
#pragma unroll
    for (int w = 0; w < 2; w++) red[u][w * 32 + b] = acc2[w];
    __syncthreads();
    if (tid < 64) {
      float s = 0.f;
#pragma unroll
      for (int uu = 0; uu < 16; uu++) s += red[uu][tid];
      int w = tid >> 5, b2 = tid & 31;
      s_mb[w][b2] = fmaxf(s + mb2[512 + i0 + w], 0.f);
    }
    __syncthreads();
    if (tid >= 64 && tid < 96) {
      int b2 = tid - 64;
      float part = w3q0 * s_mb[0][b2] + w3q1 * s_mb[1][b2];
      __hip_atomic_fetch_add(&pacc[((size_t)(Tt - 1) * 2 + 1) * 512 + grp * 32 + b2], part,
                             __ATOMIC_RELAXED, __HIP_MEMORY_SCOPE_AGENT);
    }
    __syncthreads();   // drain p1 adds before counter bump
    if (tid == 0) {
      unsigned o1 = __hip_atomic_fetch_add(&cnt1[((unsigned)(Tt - 1) * 16u + grp) * 16u], 1u,
                          __ATOMIC_RELAXED, __HIP_MEMORY_SCOPE_AGENT);
      if (o1 == 15u)
        __hip_atomic_fetch_add(&cnt2[(unsigned)(Tt - 1) * 16u], 1u,
                               __ATOMIC_RELAXED, __HIP_MEMORY_SCOPE_AGENT);
    }
    if (blockIdx.x == 0) {
      if (tid == 0) {
        while (dloadu(&cnt2[(unsigned)(Tt - 1) * 16u]) < 16u)
          __builtin_amdgcn_s_sleep(1);
      }
      __syncthreads();
      if (tid < 32) {
        const float* pp0 = pacc + ((size_t)(Tt - 1) * 2 + 0) * 512;
        const float* pp1 = pacc + ((size_t)(Tt - 1) * 2 + 1) * 512;
        float s0 = mb30, s1 = mb31;
#pragma unroll
        for (int g = 0; g < 16; g++) { s0 += pp0[g * 32 + tid]; s1 += pp1[g * 32 + tid]; }
        out[((size_t)tid * Tt + (Tt - 1)) * 2 + 0] = sigf(s0);
        out[((size_t)tid * Tt + (Tt - 1)) * 2 + 1] = sigf(s1);
      }
    }
  }
}

extern "C" void kernel_launch(void* const* d_in, const int* in_sizes, int n_in,
                              void* d_out, int out_size, void* d_ws, size_t ws_size,
                              hipStream_t stream)
{
  (void)in_sizes; (void)n_in; (void)out_size;
  const float* x    = (const float*)d_in[0];
  const float* Wih0 = (const float*)d_in[1];
  const float* Whh0 = (const float*)d_in[2];
  const float* bih0 = (const float*)d_in[3];
  const float* bhh0 = (const float*)d_in[4];
  const float* Wih  = (const float*)d_in[5];
  const float* Whh  = (const float*)d_in[6];
  const float* bih  = (const float*)d_in[7];
  const float* bhh  = (const float*)d_in[8];
  const float* mW1  = (const float*)d_in[9];
  const float* mb1  = (const float*)d_in[10];
  const float* mW2  = (const float*)d_in[11];
  const float* mb2  = (const float*)d_in[12];
  const float* mW3  = (const float*)d_in[13];
  const float* mb3  = (const float*)d_in[14];
  float* out = (float*)d_out;

  char* ws = (char*)d_ws;
  size_t off = 0;
  auto take = [&](size_t bytes) { size_t o = off; off = (off + bytes + 255) & ~(size_t)255; return o; };
  unsigned* bc1  = (unsigned*)(ws + take((size_t)NBAR * 16 * 16 * 4));
  unsigned* bc2  = (unsigned*)(ws + take((size_t)NBAR * 16 * 4));
  unsigned* gfl  = (unsigned*)(ws + take((size_t)16 * 16 * 4));
  unsigned* cnt1 = (unsigned*)(ws + take((size_t)Tt * 16 * 16 * 4));
  unsigned* cnt2 = (unsigned*)(ws + take((size_t)Tt * 16 * 4));
  float* c0R  = (float*)(ws + take((size_t)PR * HB * 4));
  float* c1R  = (float*)(ws + take((size_t)PR * HB * 4));
  float* c2R  = (float*)(ws + take((size_t)PR * HB * 4));
  float* m0aR = (float*)(ws + take((size_t)PR * HB * 4));
  float* m1aR = (float*)(ws + take((size_t)PR * HB * 4));
  float* pacc = (float*)(ws + take((size_t)Tt * 2 * 512 * 4));
  size_t zero_bytes = off;
  float* GI0 = (float*)(ws + take((size_t)Tt * G3 * Bb * 4));
  if (ws_size < off) return;  // fail visibly rather than corrupt

  hipMemsetAsync(d_ws, 0, zero_bytes, stream);
  gi0_gemm<<<dim3(Tt, G3 / 128), 256, 0, stream>>>(x, Wih0, bih0, GI0);
  hrnn_persist<<<NBLK, NTHR, 0, stream>>>(Whh0, bhh0, Wih, Whh, bih, bhh,
      mW1, mb1, mW2, mb2, mW3, mb3, GI0,
      c0R, c1R, c2R, m0aR, m1aR, pacc, bc1, bc2, gfl, cnt1, cnt2, out);
}

// Round 10
// 18460.712 us; speedup vs baseline: 1.2672x; 1.1472x over previous
//
#include <hip/hip_runtime.h>
#include <math.h>

#define Tt 512
#define Dd 768
#define Hh 512
#define Bb 32
#define G3 1536
#define HB (Hh*Bb)
#define NBLK 256
#define NTHR 512
#define NBAR (Tt*3)      // 3 grid barriers per step (S4 folded into S1 via p1 arrival counter)
#define PR 32   // state ring period (staleness window; 32 steps ~ 330MB through 4MB L2)
#define NWROW 38         // weight rows pinned in LDS per block
#define DYNF (NWROW*512 + 16*576)   // dynamic LDS floats: weights + reduction buffer

__device__ __forceinline__ float sigf(float x) { return 1.f / (1.f + expf(-x)); }

__device__ __forceinline__ float dot4f(const float4 w4, const float* v) {
  return w4.x*v[0] + w4.y*v[1] + w4.z*v[2] + w4.w*v[3];
}

// device-scope write-through store: lands at coherence point, no fence needed
__device__ __forceinline__ void dstore(float* p, float v) {
  __hip_atomic_store(p, v, __ATOMIC_RELAXED, __HIP_MEMORY_SCOPE_AGENT);
}
__device__ __forceinline__ unsigned dloadu(const unsigned* p) {
  return __hip_atomic_load(p, __ATOMIC_RELAXED, __HIP_MEMORY_SCOPE_AGENT);
}

// ---------------- grid barrier: relaxed monotone atomics, two-level tree ----
__device__ __forceinline__ void grid_barrier(unsigned* bc1, unsigned* bc2, unsigned* gfl, int idx)
{
  __syncthreads();
  if (threadIdx.x == 0) {
    const unsigned grp = (unsigned)(blockIdx.x >> 4);     // 16 groups x 16 blocks
    unsigned old = __hip_atomic_fetch_add(&bc1[((unsigned)idx * 16u + grp) * 16u], 1u,
                        __ATOMIC_RELAXED, __HIP_MEMORY_SCOPE_AGENT);
    if (old == 15u) {
      unsigned o2 = __hip_atomic_fetch_add(&bc2[(unsigned)idx * 16u], 1u,
                        __ATOMIC_RELAXED, __HIP_MEMORY_SCOPE_AGENT);
      if (o2 == 15u) {
#pragma unroll
        for (int g = 0; g < 16; ++g)
          __hip_atomic_store(&gfl[g * 16], (unsigned)(idx + 1),
                             __ATOMIC_RELAXED, __HIP_MEMORY_SCOPE_AGENT);
      }
    }
    while (__hip_atomic_load(&gfl[grp * 16], __ATOMIC_RELAXED, __HIP_MEMORY_SCOPE_AGENT)
           < (unsigned)(idx + 1))
      __builtin_amdgcn_s_sleep(1);
  }
  __syncthreads();
}

// ---------------- GI0 = x @ Wih0^T + bih0, layout [t][j][b] ----------------
__global__ __launch_bounds__(256) void gi0_gemm(const float* __restrict__ x,
                                                const float* __restrict__ Wih0,
                                                const float* __restrict__ bih0,
                                                float* __restrict__ GI0)
{
  const int t  = blockIdx.x;
  const int j0 = blockIdx.y * 128;
  const int tid = threadIdx.x;
  const int b = tid & 31, u = tid >> 5;

  __shared__ float xs[128][33];
  float acc[16];
#pragma unroll
  for (int jj = 0; jj < 16; jj++) acc[jj] = 0.f;

  for (int kbv = 0; kbv < Dd; kbv += 128) {
    __syncthreads();
    {
      int bb = tid >> 3, kg = (tid & 7) * 4;
      const float* xp = x + ((size_t)bb * Tt + t) * Dd + kbv;
#pragma unroll
      for (int q = 0; q < 4; q++) {
        float4 v = *(const float4*)(xp + kg + q * 32);
        int k = kg + q * 32;
        xs[k + 0][bb] = v.x; xs[k + 1][bb] = v.y;
        xs[k + 2][bb] = v.z; xs[k + 3][bb] = v.w;
      }
    }
    __syncthreads();
    for (int kk = 0; kk < 128; kk += 4) {
      float x0 = xs[kk][b], x1 = xs[kk + 1][b], x2 = xs[kk + 2][b], x3 = xs[kk + 3][b];
#pragma unroll
      for (int jj = 0; jj < 16; jj++) {
        const float* wp = Wih0 + (size_t)(j0 + u + 8 * jj) * Dd + kbv + kk;
        float4 w4 = *(const float4*)wp;
        acc[jj] += w4.x * x0 + w4.y * x1 + w4.z * x2 + w4.w * x3;
      }
    }
  }
#pragma unroll
  for (int jj = 0; jj < 16; jj++) {
    int j = j0 + u + 8 * jj;
    GI0[((size_t)t * G3 + j) * 32 + b] = acc[jj] + bih0[j];
  }
}

// ---------------- persistent HRNN kernel: 3 barriers/step, LDS-pinned weights ----------------
// LDS rows 0..17: S1 (gh0/gh1/gh2); 18..25: S2; 26..35: S3; 36..37: m1b.
// Row reads are uniform per half-wave -> LDS broadcast, conflict-free.
__global__ __launch_bounds__(NTHR, 1) void hrnn_persist(
    const float* __restrict__ Whh0, const float* __restrict__ bhh0,
    const float* __restrict__ Wih,  const float* __restrict__ Whh,
    const float* __restrict__ bih,  const float* __restrict__ bhh,
    const float* __restrict__ mW1,  const float* __restrict__ mb1,
    const float* __restrict__ mW2,  const float* __restrict__ mb2,
    const float* __restrict__ mW3,  const float* __restrict__ mb3,
    const float* __restrict__ GI0,
    float* __restrict__ c0R, float* __restrict__ c1R, float* __restrict__ c2R,
    float* __restrict__ m0aR, float* __restrict__ m1aR,
    float* __restrict__ pacc,
    unsigned* __restrict__ bc1, unsigned* __restrict__ bc2, unsigned* __restrict__ gfl,
    unsigned* __restrict__ cnt1, unsigned* __restrict__ cnt2,
    float* __restrict__ out)
{
  extern __shared__ float lds[];
  float* wgt  = lds;                     // [38][512] pinned weight rows (76KB)
  float* redf = lds + NWROW * 512;       // [16][576] reduction buffer (36KB)

  __shared__ float s_gh[12][32];
  __shared__ float s_pre[6][32];
  __shared__ float s_gi[6][32];
  __shared__ float s_mb[2][32];    // m0b or m1b columns of this block

  const int tid = threadIdx.x;
  const int b = tid & 31;
  const int u = tid >> 5;          // 0..15
  const int i0 = blockIdx.x * 2;
  const int kb = u * 32;
  const int grp = blockIdx.x >> 4;
  int baridx = 0;

  // ---- preload this block's 38 weight rows into LDS (once) ----
  for (int i = tid; i < NWROW * 128; i += NTHR) {
    int r = i >> 7, off = (i & 127) << 2;
    const float* src;
    if (r < 18) {
      int l = r / 6, rem = r % 6;
      int row = (rem >> 1) * 512 + i0 + (rem & 1);
      src = (l == 0) ? Whh0 + (size_t)row * 512
                     : Whh + ((size_t)(l - 1) * G3 + row) * 512;
    } else if (r < 26) {
      int w = r - 18;
      src = (w < 6) ? Wih + (size_t)((w >> 1) * 512 + i0 + (w & 1)) * 512
                    : mW1 + (size_t)(i0 + w - 6) * 512;
    } else if (r < 36) {
      int w = r - 26;
      src = (w < 6) ? Wih + (size_t)(G3 + (w >> 1) * 512 + i0 + (w & 1)) * 512
          : (w < 8) ? mW2 + (size_t)(i0 + w - 6) * 512
                    : mW1 + (size_t)(512 + i0 + (w - 8)) * 512;
    } else {
      int w = r - 36;
      src = mW2 + (size_t)(512 + i0 + w) * 512;
    }
    *(float4*)(wgt + r * 512 + off) = *(const float4*)(src + off);
  }
  __syncthreads();

  // hoisted scalars (uniform across steps)
  const float mb30 = mb3[0], mb31 = mb3[1];
  float w3p0 = 0.f, w3p1 = 0.f, w3q0 = 0.f, w3q1 = 0.f;
  if (tid >= 64 && tid < 96) {
    w3p0 = mW3[i0]; w3p1 = mW3[i0 + 1];
    w3q0 = mW3[512 + i0]; w3q1 = mW3[512 + i0 + 1];
  }

  for (int t = 0; t < Tt; t++) {
    const size_t wo = (size_t)(t & (PR - 1)) * HB;
    const size_t ro = (size_t)((t + PR - 1) & (PR - 1)) * HB;
    const float* c0o = c0R + ro;
    const float* c1o = c1R + ro;
    const float* c2o = c2R + ro;

    float a0, a1, a2, w10, w11;

    // ---- S1': publish p1(t-1); gh2 dots hide counter propagation; weights; gh0/gh1; cell0 ----
    {
      // tail prefetch: issue early so MALL latency overlaps everything below
      float pf0 = 0.f, pf1 = 0.f, pf2 = 0.f, gi_n = 0.f, gi_rz = 0.f;
      if (tid < 64) {
        int ii = tid >> 5, bb = tid & 31, idx = (i0 + ii) * 32 + bb;
        pf0 = c0o[idx]; pf1 = c1o[idx]; pf2 = c2o[idx];
        gi_n = GI0[((size_t)t * G3 + 1024 + i0 + ii) * 32 + bb];
      }
      if (tid < 128) {
        gi_rz = GI0[((size_t)t * G3 + (tid >> 6) * 512 + i0 + ((tid >> 5) & 1)) * 32 + (tid & 31)];
      }

      if (t > 0) {
        // (a) m1b(t-1) over m1aR[slot t-1]; p1 partial -> pacc[t-1]; counter bump
        const float* m1a = m1aR + ro;
        float acc2[2] = {0.f, 0.f};
        float vm[4];
#pragma unroll
        for (int q = 0; q < 4; q++) vm[q] = m1a[(kb + q) * 32 + b];
        for (int kk = 0; kk < 32; kk += 4) {
          float nm[4];
          {
            int kn = kb + (kk < 28 ? kk + 4 : 4);
#pragma unroll
            for (int q = 0; q < 4; q++) nm[q] = m1a[(kn + q) * 32 + b];
          }
#pragma unroll
          for (int w = 0; w < 2; w++) {
            float4 w4 = *(const float4*)(wgt + (36 + w) * 512 + kb + kk);
            acc2[w] += dot4f(w4, vm);
          }
#pragma unroll
          for (int q = 0; q < 4; q++) vm[q] = nm[q];
        }
#pragma unroll
        for (int w = 0; w < 2; w++) redf[u * 576 + w * 32 + b] = acc2[w];
        __syncthreads();
        if (tid < 64) {
          float s = 0.f;
#pragma unroll
          for (int uu = 0; uu < 16; uu++) s += redf[uu * 576 + tid];
          int w = tid >> 5, b2 = tid & 31;
          s_mb[w][b2] = fmaxf(s + mb2[512 + i0 + w], 0.f);      // m1b cols
        }
        __syncthreads();
        if (tid >= 64 && tid < 96) {
          int b2 = tid - 64;
          float part = w3q0 * s_mb[0][b2] + w3q1 * s_mb[1][b2];
          __hip_atomic_fetch_add(&pacc[((size_t)(t - 1) * 2 + 1) * 512 + grp * 32 + b2], part,
                                 __ATOMIC_RELAXED, __HIP_MEMORY_SCOPE_AGENT);
        }
        __syncthreads();   // vmcnt(0) drain: p1 adds at coherence point before counter bump
        if (tid == 0) {
          unsigned o1 = __hip_atomic_fetch_add(&cnt1[((unsigned)(t - 1) * 16u + grp) * 16u], 1u,
                              __ATOMIC_RELAXED, __HIP_MEMORY_SCOPE_AGENT);
          if (o1 == 15u)
            __hip_atomic_fetch_add(&cnt2[(unsigned)(t - 1) * 16u], 1u,
                                   __ATOMIC_RELAXED, __HIP_MEMORY_SCOPE_AGENT);
          // poll deferred: gh2 dots below hide the counter propagation
        }
      }

      // (b') gh2 = Whh2 @ c2o — weight-independent, runs between bump and poll.
      float acc2v[6];
#pragma unroll
      for (int w = 0; w < 6; w++) acc2v[w] = 0.f;
      {
        float v2[4];
#pragma unroll
        for (int q = 0; q < 4; q++) v2[q] = c2o[(kb + q) * 32 + b];
        for (int kk = 0; kk < 32; kk += 4) {
          float n2[4];
          {
            int kn = kb + (kk < 28 ? kk + 4 : 4);   // last iter: dummy cached re-read
#pragma unroll
            for (int q = 0; q < 4; q++) n2[q] = c2o[(kn + q) * 32 + b];
          }
#pragma unroll
          for (int w = 0; w < 6; w++) {
            float4 w4 = *(const float4*)(wgt + (12 + w) * 512 + kb + kk);
            acc2v[w] += dot4f(w4, v2);
          }
#pragma unroll
          for (int q = 0; q < 4; q++) v2[q] = n2[q];
        }
      }

      if (t > 0) {
        if (tid == 0) {
          // wait for all 16 groups' p1 contributions (normally already landed)
          while (dloadu(&cnt2[(unsigned)(t - 1) * 16u]) < 16u)
            __builtin_amdgcn_s_sleep(1);
        }
        __syncthreads();
      }

      // (c) per-thread redundant softmax weights (no cross-thread sync)
      {
        const int pslot = (t + Tt - 1) & (Tt - 1);   // t=0 -> slot 511 (zeros)
        const float* pp0 = pacc + ((size_t)pslot * 2 + 0) * 512;
        const float* pp1 = pacc + ((size_t)pslot * 2 + 1) * 512;
        float s0 = mb30, s1 = mb31;
#pragma unroll
        for (int g = 0; g < 16; g++) { s0 += pp0[g * 32 + b]; s1 += pp1[g * 32 + b]; }
        float p0 = sigf(s0), p1 = sigf(s1);
        float e0 = expf(1.f - p0), e1 = expf(p0 * (1.f - p1)), e2 = expf(p0 * p1);
        float inv = 1.f / (e0 + e1 + e2);
        a0 = e0 * inv; a1 = e1 * inv; a2 = e2 * inv;
        float q0 = expf(1.f - p1), q1 = expf(p1);
        float qi = 1.f / (q0 + q1);
        w10 = q0 * qi; w11 = q1 * qi;
        if (t > 0 && blockIdx.x == 0 && tid < 32) {
          out[((size_t)tid * Tt + (t - 1)) * 2 + 0] = p0;
          out[((size_t)tid * Tt + (t - 1)) * 2 + 1] = p1;
        }
      }

      // (d) gh0/gh1 with inline h-mixing (distance-1 pipelined); cell0
      float acc[12];
#pragma unroll
      for (int w = 0; w < 12; w++) acc[w] = 0.f;
      float v0[4], v1[4], v2[4];
#pragma unroll
      for (int q = 0; q < 4; q++) {
        int k = kb + q;
        v0[q] = c0o[k * 32 + b]; v1[q] = c1o[k * 32 + b]; v2[q] = c2o[k * 32 + b];
      }
      for (int kk = 0; kk < 32; kk += 4) {
        float n0[4], n1[4], n2[4];
        {
          int kn = kb + (kk < 28 ? kk + 4 : 4);   // last iter: dummy cached re-read
#pragma unroll
          for (int q = 0; q < 4; q++) {
            n0[q] = c0o[(kn + q) * 32 + b];
            n1[q] = c1o[(kn + q) * 32 + b];
            n2[q] = c2o[(kn + q) * 32 + b];
          }
        }
        float mh0[4], mh1[4];
#pragma unroll
        for (int q = 0; q < 4; q++) {
          mh0[q] = a0 * v0[q] + a1 * v1[q] + a2 * v2[q];
          mh1[q] = w10 * v1[q] + w11 * v2[q];
        }
#pragma unroll
        for (int w = 0; w < 12; w++) {
          float4 w4 = *(const float4*)(wgt + w * 512 + kb + kk);
          acc[w] += (w < 6) ? dot4f(w4, mh0) : dot4f(w4, mh1);
        }
#pragma unroll
        for (int q = 0; q < 4; q++) { v0[q] = n0[q]; v1[q] = n1[q]; v2[q] = n2[q]; }
      }
#pragma unroll
      for (int w = 0; w < 12; w++) redf[u * 576 + w * 32 + b] = acc[w];
#pragma unroll
      for (int w = 0; w < 6; w++) redf[u * 576 + (12 + w) * 32 + b] = acc2v[w];
      __syncthreads();
      for (int o = tid; o < 18 * 32; o += NTHR) {
        float s = 0.f;
#pragma unroll
        for (int uu = 0; uu < 16; uu++) s += redf[uu * 576 + o];
        int w = o >> 5, b2 = o & 31;
        int l = w / 6, rem = w % 6, g = rem >> 1, ii = rem & 1;
        int row = g * 512 + i0 + ii;
        if (l == 0) {
          s += bhh0[row];
          if (g < 2) s += gi_rz;          // prefetched GI0 r/z (first o-pass only)
          s_pre[rem][b2] = s;
        } else if (l == 1) {
          s_gh[rem][b2] = s + bhh[row];
        } else {
          s_gh[6 + rem][b2] = s + bhh[G3 + row];
        }
      }
      __syncthreads();
      if (tid < 64) {
        int ii = tid >> 5, bb = tid & 31;
        float r = sigf(s_pre[ii][bb]);
        float z = sigf(s_pre[2 + ii][bb]);
        float n = tanhf(gi_n + r * s_pre[4 + ii][bb]);
        int idx = (i0 + ii) * 32 + bb;
        float h0old = a0 * pf0 + a1 * pf1 + a2 * pf2;
        dstore(&c0R[wo + idx], (1.f - z) * n + z * h0old);
      }
    }
    grid_barrier(bc1, bc2, gfl, baridx++);

    // ---- S2: gi1 (over cell0) + m0a; cell1 ----
    {
      float pf1 = 0.f, pf2 = 0.f;
      if (tid < 64) {
        int ii = tid >> 5, bb = tid & 31, idx = (i0 + ii) * 32 + bb;
        pf1 = c1o[idx]; pf2 = c2o[idx];
      }
      const float* c0n = c0R + wo;
      float acc[8];
#pragma unroll
      for (int w = 0; w < 8; w++) acc[w] = 0.f;
      float v[4];
#pragma unroll
      for (int q = 0; q < 4; q++) v[q] = c0n[(kb + q) * 32 + b];
      for (int kk = 0; kk < 32; kk += 4) {
        float nv[4];
        {
          int kn = kb + (kk < 28 ? kk + 4 : 4);
#pragma unroll
          for (int q = 0; q < 4; q++) nv[q] = c0n[(kn + q) * 32 + b];
        }
#pragma unroll
        for (int w = 0; w < 8; w++) {
          float4 w4 = *(const float4*)(wgt + (18 + w) * 512 + kb + kk);
          acc[w] += dot4f(w4, v);
        }
#pragma unroll
        for (int q = 0; q < 4; q++) v[q] = nv[q];
      }
#pragma unroll
      for (int w = 0; w < 8; w++) redf[u * 576 + w * 32 + b] = acc[w];
      __syncthreads();
      for (int o = tid; o < 8 * 32; o += NTHR) {
        float s = 0.f;
#pragma unroll
        for (int uu = 0; uu < 16; uu++) s += redf[uu * 576 + o];
        int w = o >> 5, b2 = o & 31;
        if (w < 6) {
          int row = (w >> 1) * 512 + i0 + (w & 1);
          s_gi[w][b2] = s + bih[row];
        } else {
          int col = i0 + (w - 6);
          dstore(&m0aR[wo + col * 32 + b2], fmaxf(s + mb1[col], 0.f));
        }
      }
      __syncthreads();
      if (tid < 64) {
        int ii = tid >> 5, bb = tid & 31;
        float r = sigf(s_gi[ii][bb] + s_gh[ii][bb]);
        float z = sigf(s_gi[2 + ii][bb] + s_gh[2 + ii][bb]);
        float n = tanhf(s_gi[4 + ii][bb] + r * s_gh[4 + ii][bb]);
        int idx = (i0 + ii) * 32 + bb;
        float h1old = w10 * pf1 + w11 * pf2;
        dstore(&c1R[wo + idx], (1.f - z) * n + z * h1old);
      }
    }
    grid_barrier(bc1, bc2, gfl, baridx++);

    // ---- S3: gi2 (over cell1) + m0b (over m0a) + m1a (over cell1); cell2; p0 partials ----
    {
      float pf2 = 0.f;
      if (tid < 64) {
        int ii = tid >> 5, bb = tid & 31;
        pf2 = c2o[(i0 + ii) * 32 + bb];
      }
      const float* c1n = c1R + wo;
      const float* m0a = m0aR + wo;
      float acc[10];
#pragma unroll
      for (int w = 0; w < 10; w++) acc[w] = 0.f;
      float v[4], vm[4];
#pragma unroll
      for (int q = 0; q < 4; q++) {
        v[q]  = c1n[(kb + q) * 32 + b];
        vm[q] = m0a[(kb + q) * 32 + b];
      }
      for (int kk = 0; kk < 32; kk += 4) {
        float nv[4], nm[4];
        {
          int kn = kb + (kk < 28 ? kk + 4 : 4);
#pragma unroll
          for (int q = 0; q < 4; q++) {
            nv[q] = c1n[(kn + q) * 32 + b];
            nm[q] = m0a[(kn + q) * 32 + b];
          }
        }
#pragma unroll
        for (int w = 0; w < 10; w++) {
          float4 w4 = *(const float4*)(wgt + (26 + w) * 512 + kb + kk);
          acc[w] += dot4f(w4, (w < 6 || w >= 8) ? v : vm);
        }
#pragma unroll
        for (int q = 0; q < 4; q++) { v[q] = nv[q]; vm[q] = nm[q]; }
      }
#pragma unroll
      for (int w = 0; w < 10; w++) redf[u * 576 + w * 32 + b] = acc[w];
      __syncthreads();
      for (int o = tid; o < 10 * 32; o += NTHR) {
        float s = 0.f;
#pragma unroll
        for (int uu = 0; uu < 16; uu++) s += redf[uu * 576 + o];
        int w = o >> 5, b2 = o & 31;
        if (w < 6) {
          int row = (w >> 1) * 512 + i0 + (w & 1);
          s_gi[w][b2] = s + bih[G3 + row];
        } else if (w < 8) {
          s_mb[w - 6][b2] = fmaxf(s + mb2[i0 + (w - 6)], 0.f);   // m0b cols
        } else {
          int col = i0 + (w - 8);
          dstore(&m1aR[wo + col * 32 + b2], fmaxf(s + mb1[512 + col], 0.f));
        }
      }
      __syncthreads();
      if (tid < 64) {
        int ii = tid >> 5, bb = tid & 31;
        float r = sigf(s_gi[ii][bb] + s_gh[6 + ii][bb]);
        float z = sigf(s_gi[2 + ii][bb] + s_gh[8 + ii][bb]);
        float n = tanhf(s_gi[4 + ii][bb] + r * s_gh[10 + ii][bb]);
        int idx = (i0 + ii) * 32 + bb;
        dstore(&c2R[wo + idx], (1.f - z) * n + z * pf2);
      } else if (tid < 96) {
        int b2 = tid - 64;
        float part = w3p0 * s_mb[0][b2] + w3p1 * s_mb[1][b2];
        __hip_atomic_fetch_add(&pacc[((size_t)t * 2 + 0) * 512 + grp * 32 + b2], part,
                               __ATOMIC_RELAXED, __HIP_MEMORY_SCOPE_AGENT);
      }
    }
    grid_barrier(bc1, bc2, gfl, baridx++);
  }

  // ---- epilogue: publish p1(T-1) and write final out column ----
  {
    const size_t rofin = (size_t)((Tt - 1) & (PR - 1)) * HB;
    const float* m1a = m1aR + rofin;
    float acc2[2] = {0.f, 0.f};
    for (int kk = 0; kk < 32; kk += 4) {
      float vm[4];
#pragma unroll
      for (int q = 0; q < 4; q++) vm[q] = m1a[(kb + kk + q) * 32 + b];
#pragma unroll
      for (int w = 0; w < 2; w++) {
        float4 w4 = *(const float4*)(wgt + (36 + w) * 512 + kb + kk);
        acc2[w] += dot4f(w4, vm);
      }
    }
#pragma unroll
    for (int w = 0; w < 2; w++) redf[u * 576 + w * 32 + b] = acc2[w];
    __syncthreads();
    if (tid < 64) {
      float s = 0.f;
#pragma unroll
      for (int uu = 0; uu < 16; uu++) s += redf[uu * 576 + tid];
      int w = tid >> 5, b2 = tid & 31;
      s_mb[w][b2] = fmaxf(s + mb2[512 + i0 + w], 0.f);
    }
    __syncthreads();
    if (tid >= 64 && tid < 96) {
      int b2 = tid - 64;
      float part = w3q0 * s_mb[0][b2] + w3q1 * s_mb[1][b2];
      __hip_atomic_fetch_add(&pacc[((size_t)(Tt - 1) * 2 + 1) * 512 + grp * 32 + b2], part,
                             __ATOMIC_RELAXED, __HIP_MEMORY_SCOPE_AGENT);
    }
    __syncthreads();   // drain p1 adds before counter bump
    if (tid == 0) {
      unsigned o1 = __hip_atomic_fetch_add(&cnt1[((unsigned)(Tt - 1) * 16u + grp) * 16u], 1u,
                          __ATOMIC_RELAXED, __HIP_MEMORY_SCOPE_AGENT);
      if (o1 == 15u)
        __hip_atomic_fetch_add(&cnt2[(unsigned)(Tt - 1) * 16u], 1u,
                               __ATOMIC_RELAXED, __HIP_MEMORY_SCOPE_AGENT);
    }
    if (blockIdx.x == 0) {
      if (tid == 0) {
        while (dloadu(&cnt2[(unsigned)(Tt - 1) * 16u]) < 16u)
          __builtin_amdgcn_s_sleep(1);
      }
      __syncthreads();
      if (tid < 32) {
        const float* pp0 = pacc + ((size_t)(Tt - 1) * 2 + 0) * 512;
        const float* pp1 = pacc + ((size_t)(Tt - 1) * 2 + 1) * 512;
        float s0 = mb30, s1 = mb31;
#pragma unroll
        for (int g = 0; g < 16; g++) { s0 += pp0[g * 32 + tid]; s1 += pp1[g * 32 + tid]; }
        out[((size_t)tid * Tt + (Tt - 1)) * 2 + 0] = sigf(s0);
        out[((size_t)tid * Tt + (Tt - 1)) * 2 + 1] = sigf(s1);
      }
    }
  }
}

extern "C" void kernel_launch(void* const* d_in, const int* in_sizes, int n_in,
                              void* d_out, int out_size, void* d_ws, size_t ws_size,
                              hipStream_t stream)
{
  (void)in_sizes; (void)n_in; (void)out_size;
  const float* x    = (const float*)d_in[0];
  const float* Wih0 = (const float*)d_in[1];
  const float* Whh0 = (const float*)d_in[2];
  const float* bih0 = (const float*)d_in[3];
  const float* bhh0 = (const float*)d_in[4];
  const float* Wih  = (const float*)d_in[5];
  const float* Whh  = (const float*)d_in[6];
  const float* bih  = (const float*)d_in[7];
  const float* bhh  = (const float*)d_in[8];
  const float* mW1  = (const float*)d_in[9];
  const float* mb1  = (const float*)d_in[10];
  const float* mW2  = (const float*)d_in[11];
  const float* mb2  = (const float*)d_in[12];
  const float* mW3  = (const float*)d_in[13];
  const float* mb3  = (const float*)d_in[14];
  float* out = (float*)d_out;

  char* ws = (char*)d_ws;
  size_t off = 0;
  auto take = [&](size_t bytes) { size_t o = off; off = (off + bytes + 255) & ~(size_t)255; return o; };
  unsigned* bc1  = (unsigned*)(ws + take((size_t)NBAR * 16 * 16 * 4));
  unsigned* bc2  = (unsigned*)(ws + take((size_t)NBAR * 16 * 4));
  unsigned* gfl  = (unsigned*)(ws + take((size_t)16 * 16 * 4));
  unsigned* cnt1 = (unsigned*)(ws + take((size_t)Tt * 16 * 16 * 4));
  unsigned* cnt2 = (unsigned*)(ws + take((size_t)Tt * 16 * 4));
  float* c0R  = (float*)(ws + take((size_t)PR * HB * 4));
  float* c1R  = (float*)(ws + take((size_t)PR * HB * 4));
  float* c2R  = (float*)(ws + take((size_t)PR * HB * 4));
  float* m0aR = (float*)(ws + take((size_t)PR * HB * 4));
  float* m1aR = (float*)(ws + take((size_t)PR * HB * 4));
  float* pacc = (float*)(ws + take((size_t)Tt * 2 * 512 * 4));
  size_t zero_bytes = off;
  float* GI0 = (float*)(ws + take((size_t)Tt * G3 * Bb * 4));
  if (ws_size < off) return;  // fail visibly rather than corrupt

  const int dyn_bytes = DYNF * 4;   // 114,688 B dynamic LDS (weights + reduction)
  hipFuncSetAttribute(reinterpret_cast<const void*>(hrnn_persist),
                      hipFuncAttributeMaxDynamicSharedMemorySize, dyn_bytes);

  hipMemsetAsync(d_ws, 0, zero_bytes, stream);
  gi0_gemm<<<dim3(Tt, G3 / 128), 256, 0, stream>>>(x, Wih0, bih0, GI0);
  hrnn_persist<<<NBLK, NTHR, dyn_bytes, stream>>>(Whh0, bhh0, Wih, Whh, bih, bhh,
      mW1, mb1, mW2, mb2, mW3, mb3, GI0,
      c0R, c1R, c2R, m0aR, m1aR, pacc, bc1, bc2, gfl, cnt1, cnt2, out);
}